// Round 1
// baseline (199.658 us; speedup 1.0000x reference)
//
#include <hip/hip_runtime.h>
#include <math.h>

#define N_SAMPLES 64
#define N_ENT     10000
#define D         256
#define K         10
#define STRIPS    16
#define STRIP_LEN (N_ENT / STRIPS)   // 625
#define TPB       256

// ---------- comparators (match lax.top_k: ties -> lower index first) ----------
__device__ __forceinline__ bool better_top(double v, int i, double v2, int i2) {
    return (v > v2) || (v == v2 && i < i2);
}
__device__ __forceinline__ bool better_bot(double v, int i, double v2, int i2) {
    return (v < v2) || (v == v2 && i < i2);
}

// merge two sorted K-lists (slots A and B in LDS) -> top-K into slot A
template <bool TOP>
__device__ __forceinline__ void merge_lds(double* lv, int* li, int A, int B) {
    double ov[K]; int oi[K];
    int a = 0, b = 0;
#pragma unroll
    for (int o = 0; o < K; ++o) {
        double va = lv[A * K + a]; int ia = li[A * K + a];
        double vb = lv[B * K + b]; int ib = li[B * K + b];
        bool pick = TOP ? better_top(va, ia, vb, ib) : better_bot(va, ia, vb, ib);
        ov[o] = pick ? va : vb;
        oi[o] = pick ? ia : ib;
        if (pick) ++a; else ++b;
    }
#pragma unroll
    for (int o = 0; o < K; ++o) { lv[A * K + o] = ov[o]; li[A * K + o] = oi[o]; }
}

// ---------- kernel 0: per-entity f64 row sums ----------
__global__ __launch_bounds__(256) void ent_sums(const float* __restrict__ E,
                                                double* __restrict__ Se) {
    int j = blockIdx.x * blockDim.x + threadIdx.x;
    if (j >= N_ENT) return;
    const float4* e4 = reinterpret_cast<const float4*>(E + (size_t)j * D);
    double s0 = 0, s1 = 0, s2 = 0, s3 = 0;
#pragma unroll 4
    for (int d4 = 0; d4 < D / 4; ++d4) {
        float4 v = e4[d4];
        s0 += (double)v.x; s1 += (double)v.y; s2 += (double)v.z; s3 += (double)v.w;
    }
    Se[j] = (s0 + s1) + (s2 + s3);
}

// ---------- kernel 1: jaccard + per-(query,strip) top/bot-10 ----------
__global__ __launch_bounds__(TPB) void jac_topk_part(
        const float* __restrict__ Q, const float* __restrict__ E,
        const double* __restrict__ Se,
        double* __restrict__ tval, double* __restrict__ bval,
        int* __restrict__ tidx, int* __restrict__ bidx) {
    const int bid   = blockIdx.x;
    const int strip = bid & (STRIPS - 1);   // bid%8 == strip%8 -> strip pinned to one XCD's L2
    const int q     = bid >> 4;
    const int tid   = threadIdx.x;

    __shared__ float4 qs4[D / 4];           // 1 KB
    __shared__ double lv[TPB * K];          // 20 KB
    __shared__ int    li[TPB * K];          // 10 KB

    if (tid < D / 4)
        qs4[tid] = reinterpret_cast<const float4*>(Q + (size_t)q * D)[tid];
    __syncthreads();

    // Sq (redundant per thread, one-time)
    double Sq = 0;
#pragma unroll
    for (int d4 = 0; d4 < D / 4; ++d4) {
        float4 v = qs4[d4];
        Sq += (double)v.x; Sq += (double)v.y; Sq += (double)v.z; Sq += (double)v.w;
    }

    double tv[K]; int ti[K]; double bv[K]; int bi[K];
#pragma unroll
    for (int o = 0; o < K; ++o) {
        tv[o] = -INFINITY; ti[o] = 0x7fffffff;
        bv[o] =  INFINITY; bi[o] = 0x7fffffff;
    }

    const int base = strip * STRIP_LEN;
    for (int j = base + tid; j < base + STRIP_LEN; j += TPB) {
        const float4* e4 = reinterpret_cast<const float4*>(E + (size_t)j * D);
        double a0 = 0, a1 = 0, a2 = 0, a3 = 0;
#pragma unroll 4
        for (int d4 = 0; d4 < D / 4; ++d4) {
            float4 ev = e4[d4];
            float4 qv = qs4[d4];
            a0 += (double)fminf(qv.x, ev.x);
            a1 += (double)fminf(qv.y, ev.y);
            a2 += (double)fminf(qv.z, ev.z);
            a3 += (double)fminf(qv.w, ev.w);
        }
        double inter = (a0 + a1) + (a2 + a3);
        double uni   = Sq + Se[j] - inter;   // min+max == q+e exactly
        double jac   = inter / uni;

        // top insertion (fully unrolled -> stays in registers)
        if (better_top(jac, j, tv[K - 1], ti[K - 1])) {
            tv[K - 1] = jac; ti[K - 1] = j;
#pragma unroll
            for (int s = K - 1; s > 0; --s) {
                if (better_top(tv[s], ti[s], tv[s - 1], ti[s - 1])) {
                    double tmv = tv[s]; tv[s] = tv[s - 1]; tv[s - 1] = tmv;
                    int    tmi = ti[s]; ti[s] = ti[s - 1]; ti[s - 1] = tmi;
                }
            }
        }
        // bot insertion
        if (better_bot(jac, j, bv[K - 1], bi[K - 1])) {
            bv[K - 1] = jac; bi[K - 1] = j;
#pragma unroll
            for (int s = K - 1; s > 0; --s) {
                if (better_bot(bv[s], bi[s], bv[s - 1], bi[s - 1])) {
                    double tmv = bv[s]; bv[s] = bv[s - 1]; bv[s - 1] = tmv;
                    int    tmi = bi[s]; bi[s] = bi[s - 1]; bi[s - 1] = tmi;
                }
            }
        }
    }

    // ---- block tree-merge: TOP ----
#pragma unroll
    for (int o = 0; o < K; ++o) { lv[tid * K + o] = tv[o]; li[tid * K + o] = ti[o]; }
    __syncthreads();
    for (int s = TPB / 2; s >= 1; s >>= 1) {
        if (tid < s) merge_lds<true>(lv, li, tid, tid + s);
        __syncthreads();
    }
    if (tid == 0) {
        const size_t slot = ((size_t)q * STRIPS + strip) * K;
#pragma unroll
        for (int o = 0; o < K; ++o) { tval[slot + o] = lv[o]; tidx[slot + o] = li[o]; }
    }
    __syncthreads();

    // ---- block tree-merge: BOT ----
#pragma unroll
    for (int o = 0; o < K; ++o) { lv[tid * K + o] = bv[o]; li[tid * K + o] = bi[o]; }
    __syncthreads();
    for (int s = TPB / 2; s >= 1; s >>= 1) {
        if (tid < s) merge_lds<false>(lv, li, tid, tid + s);
        __syncthreads();
    }
    if (tid == 0) {
        const size_t slot = ((size_t)q * STRIPS + strip) * K;
#pragma unroll
        for (int o = 0; o < K; ++o) { bval[slot + o] = lv[o]; bidx[slot + o] = li[o]; }
    }
}

// ---------- kernel 2: merge 16 strip lists per query, write indices ----------
__global__ __launch_bounds__(64) void final_merge(
        const double* __restrict__ tval, const double* __restrict__ bval,
        const int* __restrict__ tidx, const int* __restrict__ bidx,
        int* __restrict__ out) {
    const int q = blockIdx.x;
    const int tid = threadIdx.x;
    __shared__ double lv[STRIPS * K];
    __shared__ int    li[STRIPS * K];

    // TOP
    if (tid < STRIPS) {
        const size_t slot = ((size_t)q * STRIPS + tid) * K;
#pragma unroll
        for (int o = 0; o < K; ++o) { lv[tid * K + o] = tval[slot + o]; li[tid * K + o] = tidx[slot + o]; }
    }
    __syncthreads();
    for (int s = STRIPS / 2; s >= 1; s >>= 1) {
        if (tid < s) merge_lds<true>(lv, li, tid, tid + s);
        __syncthreads();
    }
    if (tid == 0) {
#pragma unroll
        for (int o = 0; o < K; ++o) out[q * K + o] = li[o];
    }
    __syncthreads();

    // BOT
    if (tid < STRIPS) {
        const size_t slot = ((size_t)q * STRIPS + tid) * K;
#pragma unroll
        for (int o = 0; o < K; ++o) { lv[tid * K + o] = bval[slot + o]; li[tid * K + o] = bidx[slot + o]; }
    }
    __syncthreads();
    for (int s = STRIPS / 2; s >= 1; s >>= 1) {
        if (tid < s) merge_lds<false>(lv, li, tid, tid + s);
        __syncthreads();
    }
    if (tid == 0) {
#pragma unroll
        for (int o = 0; o < K; ++o) out[N_SAMPLES * K + q * K + o] = li[o];
    }
}

extern "C" void kernel_launch(void* const* d_in, const int* in_sizes, int n_in,
                              void* d_out, int out_size, void* d_ws, size_t ws_size,
                              hipStream_t stream) {
    const float* Q = (const float*)d_in[0];   // [64, 256]
    const float* E = (const float*)d_in[1];   // [10000, 256]
    int* out = (int*)d_out;                   // 640 top idx + 640 bot idx

    // workspace layout (326 KB total)
    char* ws = (char*)d_ws;
    double* Se   = (double*)(ws);             // 10000 * 8  = 80000
    double* tval = (double*)(ws + 80000);     // 10240 * 8  = 81920
    double* bval = (double*)(ws + 161920);    // 10240 * 8  = 81920
    int*    tidx = (int*)   (ws + 243840);    // 10240 * 4  = 40960
    int*    bidx = (int*)   (ws + 284800);    // 10240 * 4  = 40960

    hipLaunchKernelGGL(ent_sums, dim3((N_ENT + 255) / 256), dim3(256), 0, stream, E, Se);
    hipLaunchKernelGGL(jac_topk_part, dim3(N_SAMPLES * STRIPS), dim3(TPB), 0, stream,
                       Q, E, Se, tval, bval, tidx, bidx);
    hipLaunchKernelGGL(final_merge, dim3(N_SAMPLES), dim3(64), 0, stream,
                       tval, bval, tidx, bidx, out);
}

// Round 2
// 98.761 us; speedup vs baseline: 2.0216x; 2.0216x over previous
//
#include <hip/hip_runtime.h>
#include <math.h>
#include <limits.h>

#define NQ   64
#define NE   10000
#define D    256
#define G4   (D / 4)      // 64 float4 groups per row
#define K    10
#define NBLK 500          // blocks in kernel 1 == partial lists per query
#define EPB  20           // entities per block (500*20 = 10000 exactly)
#define TPB1 512
#define WAVES 8

// ---------- comparators (match lax.top_k: ties -> lower index first) ----------
__device__ __forceinline__ bool better_top(double v, int i, double v2, int i2) {
    return (v > v2) || (v == v2 && i < i2);
}
__device__ __forceinline__ bool better_bot(double v, int i, double v2, int i2) {
    return (v < v2) || (v == v2 && i < i2);
}

// merge two sorted K-lists living in LDS (slot indices A, B) -> result into slot A
template <bool TOP>
__device__ __forceinline__ void merge_slots(double* Mv, int* Mi, int A, int B) {
    double ov[K]; int oi[K];
    int a = 0, b = 0;
#pragma unroll
    for (int o = 0; o < K; ++o) {
        double va = Mv[A * K + a]; int ia = Mi[A * K + a];
        double vb = Mv[B * K + b]; int ib = Mi[B * K + b];
        bool pick = TOP ? better_top(va, ia, vb, ib) : better_bot(va, ia, vb, ib);
        ov[o] = pick ? va : vb;
        oi[o] = pick ? ia : ib;
        if (pick) ++a; else ++b;
    }
#pragma unroll
    for (int o = 0; o < K; ++o) { Mv[A * K + o] = ov[o]; Mi[A * K + o] = oi[o]; }
}

// ---------------- kernel 1: lane = query, stream entities once ----------------
// LDS layout (dynamic, 73728 B):
//   [0, 65536)        QT float4[G4][64]  (query, transposed; reused as merge buf)
//   [65536, 69632)    SqP double[8][64]  (transient, then reused as ebuf)
//   [65536, 73728)    ebuf: 1 KB per wave (8 waves)
__global__ __launch_bounds__(TPB1, 3) void jac_part(
        const float* __restrict__ Q, const float* __restrict__ E,
        double* __restrict__ tval, double* __restrict__ bval,
        int* __restrict__ tidx, int* __restrict__ bidx) {
    extern __shared__ char smem[];
    float4*  QT  = (float4*)smem;
    double*  SqP = (double*)(smem + 65536);

    const int t = threadIdx.x;
    const int l = t & 63;      // lane = query index
    const int w = t >> 6;      // wave index 0..7
    const int b = blockIdx.x;

    // ---- stage Q transposed + Sq partial sums ----
    double sqp = 0.0;
#pragma unroll
    for (int r = 0; r < 8; ++r) {
        int g = w + 8 * r;
        float4 v = reinterpret_cast<const float4*>(Q)[l * G4 + g];
        QT[g * 64 + l] = v;                       // consecutive lanes -> consecutive 16B
        sqp += ((double)v.x + (double)v.y) + ((double)v.z + (double)v.w);
    }
    SqP[w * 64 + l] = sqp;
    __syncthreads();
    double Sq = 0.0;
#pragma unroll
    for (int p = 0; p < 8; ++p) Sq += SqP[p * 64 + l];   // same order for all threads of query l
    __syncthreads();                                      // SqP region free -> ebuf

    float4* eb = (float4*)(smem + 65536 + (w << 10));     // wave-private 1 KB row buffer

    double tv[K]; int ti[K]; double bv[K]; int bi[K];
#pragma unroll
    for (int o = 0; o < K; ++o) {
        tv[o] = -INFINITY; ti[o] = INT_MAX;
        bv[o] =  INFINITY; bi[o] = INT_MAX;
    }

    // ---- entity loop: wave-local, no block barriers (waves have unequal counts) ----
    for (int i = w; i < EPB; i += WAVES) {
        const int j = b * EPB + i;
        // coalesced: 64 lanes x 16B = exactly one entity row
        float4 er = reinterpret_cast<const float4*>(E)[(size_t)j * G4 + l];

        // exact f64 row sum of entity via butterfly (all lanes end with Se_j)
        double se = ((double)er.x + (double)er.y) + ((double)er.z + (double)er.w);
#pragma unroll
        for (int m = 1; m < 64; m <<= 1) se += __shfl_xor(se, m, 64);

        eb[l] = er;   // wave-local LDS staging; in-order DS ops make this safe intra-wave

        double a0 = 0, a1 = 0, a2 = 0, a3 = 0;
#pragma unroll 4
        for (int g = 0; g < G4; ++g) {
            float4 qv = QT[g * 64 + l];   // conflict-free
            float4 ev = eb[g];            // uniform address -> broadcast
            a0 += (double)fminf(qv.x, ev.x);
            a1 += (double)fminf(qv.y, ev.y);
            a2 += (double)fminf(qv.z, ev.z);
            a3 += (double)fminf(qv.w, ev.w);
        }
        double inter = (a0 + a1) + (a2 + a3);
        double uni   = Sq + se - inter;    // min+max == q+e exactly
        double jac   = inter / uni;

        if (better_top(jac, j, tv[K - 1], ti[K - 1])) {
            tv[K - 1] = jac; ti[K - 1] = j;
#pragma unroll
            for (int s = K - 1; s > 0; --s) {
                if (better_top(tv[s], ti[s], tv[s - 1], ti[s - 1])) {
                    double tm = tv[s]; tv[s] = tv[s - 1]; tv[s - 1] = tm;
                    int    ii = ti[s]; ti[s] = ti[s - 1]; ti[s - 1] = ii;
                }
            }
        }
        if (better_bot(jac, j, bv[K - 1], bi[K - 1])) {
            bv[K - 1] = jac; bi[K - 1] = j;
#pragma unroll
            for (int s = K - 1; s > 0; --s) {
                if (better_bot(bv[s], bi[s], bv[s - 1], bi[s - 1])) {
                    double tm = bv[s]; bv[s] = bv[s - 1]; bv[s - 1] = tm;
                    int    ii = bi[s]; bi[s] = bi[s - 1]; bi[s - 1] = ii;
                }
            }
        }
    }

    // ---- in-block merge across 8 waves (per query), reusing QT space ----
    __syncthreads();
    double* Mv = (double*)smem;              // 8*64*10*8 = 40960 B
    int*    Mi = (int*)(smem + 40960);       // 8*64*10*4 = 20480 B

    // TOP
#pragma unroll
    for (int o = 0; o < K; ++o) { Mv[(w * 64 + l) * K + o] = tv[o]; Mi[(w * 64 + l) * K + o] = ti[o]; }
    __syncthreads();
    for (int s = 4; s >= 1; s >>= 1) {
        if (w < s) merge_slots<true>(Mv, Mi, w * 64 + l, (w + s) * 64 + l);
        __syncthreads();
    }
    if (w == 0) {
        const size_t slot = ((size_t)l * NBLK + b) * K;
#pragma unroll
        for (int o = 0; o < K; ++o) { tval[slot + o] = Mv[l * K + o]; tidx[slot + o] = Mi[l * K + o]; }
    }
    __syncthreads();

    // BOT
#pragma unroll
    for (int o = 0; o < K; ++o) { Mv[(w * 64 + l) * K + o] = bv[o]; Mi[(w * 64 + l) * K + o] = bi[o]; }
    __syncthreads();
    for (int s = 4; s >= 1; s >>= 1) {
        if (w < s) merge_slots<false>(Mv, Mi, w * 64 + l, (w + s) * 64 + l);
        __syncthreads();
    }
    if (w == 0) {
        const size_t slot = ((size_t)l * NBLK + b) * K;
#pragma unroll
        for (int o = 0; o < K; ++o) { bval[slot + o] = Mv[l * K + o]; bidx[slot + o] = Mi[l * K + o]; }
    }
}

// ---------------- kernel 2: merge 500 partial lists per query ----------------
template <bool TOP>
__device__ __forceinline__ void merge_query(const double* __restrict__ V,
                                            const int* __restrict__ I,
                                            double* Mv, int* Mi,
                                            int* __restrict__ outp) {
    const int t = threadIdx.x;
    // phase A: fold lists t and t+256 (global) into LDS slot t
    double ov[K]; int oi[K];
    const int lb = t + 256;
    if (lb < NBLK) {
        int a = 0, bn = 0;
#pragma unroll
        for (int o = 0; o < K; ++o) {
            double va = V[t * K + a];  int ia = I[t * K + a];
            double vb = V[lb * K + bn]; int ib = I[lb * K + bn];
            bool pick = TOP ? better_top(va, ia, vb, ib) : better_bot(va, ia, vb, ib);
            ov[o] = pick ? va : vb;
            oi[o] = pick ? ia : ib;
            if (pick) ++a; else ++bn;
        }
    } else {
#pragma unroll
        for (int o = 0; o < K; ++o) { ov[o] = V[t * K + o]; oi[o] = I[t * K + o]; }
    }
#pragma unroll
    for (int o = 0; o < K; ++o) { Mv[t * K + o] = ov[o]; Mi[t * K + o] = oi[o]; }
    __syncthreads();
    for (int s = 128; s >= 1; s >>= 1) {
        if (t < s) merge_slots<TOP>(Mv, Mi, t, t + s);
        __syncthreads();
    }
    if (t == 0) {
#pragma unroll
        for (int o = 0; o < K; ++o) outp[o] = Mi[o];
    }
    __syncthreads();
}

__global__ __launch_bounds__(256) void final_merge(
        const double* __restrict__ tval, const double* __restrict__ bval,
        const int* __restrict__ tidx, const int* __restrict__ bidx,
        int* __restrict__ out) {
    __shared__ double Mv[256 * K];   // 20480 B
    __shared__ int    Mi[256 * K];   // 10240 B
    const int q = blockIdx.x;
    merge_query<true >(tval + (size_t)q * NBLK * K, tidx + (size_t)q * NBLK * K,
                       Mv, Mi, out + q * K);
    merge_query<false>(bval + (size_t)q * NBLK * K, bidx + (size_t)q * NBLK * K,
                       Mv, Mi, out + NQ * K + q * K);
}

extern "C" void kernel_launch(void* const* d_in, const int* in_sizes, int n_in,
                              void* d_out, int out_size, void* d_ws, size_t ws_size,
                              hipStream_t stream) {
    const float* Q = (const float*)d_in[0];   // [64, 256]
    const float* E = (const float*)d_in[1];   // [10000, 256]
    int* out = (int*)d_out;                   // 640 top idx + 640 bot idx

    // workspace layout (7.68 MB total)
    char* ws = (char*)d_ws;
    double* tval = (double*)(ws);                 // 64*500*10*8 = 2,560,000
    double* bval = (double*)(ws + 2560000);       // 2,560,000
    int*    tidx = (int*)   (ws + 5120000);       // 1,280,000
    int*    bidx = (int*)   (ws + 6400000);       // 1,280,000

    hipLaunchKernelGGL(jac_part, dim3(NBLK), dim3(TPB1), 73728, stream,
                       Q, E, tval, bval, tidx, bidx);
    hipLaunchKernelGGL(final_merge, dim3(NQ), dim3(256), 0, stream,
                       tval, bval, tidx, bidx, out);
}